// Round 1
// baseline (950.258 us; speedup 1.0000x reference)
//
#include <hip/hip_runtime.h>
#include <math.h>

#define DIM      512
#define K_CODES  8192
#define N_ROWS   8192

#define BM 64          // rows per block tile
#define BN 64          // codes per block tile
#define BD 32          // depth tile
#define KSPLIT 16      // codebook split across blocks
#define KCHUNK (K_CODES / KSPLIT)   // 512 codes per block
#define LDE 68         // padded LDS leading dim (68*4B = 272B, 16B-aligned rows)

// ---------------------------------------------------------------------------
// Kernel 1: e_sq[k] = sum_d E[k][d]^2   (one wave per code row)
// ---------------------------------------------------------------------------
__global__ void esq_kernel(const float* __restrict__ E, float* __restrict__ e_sq) {
    const int wave = threadIdx.x >> 6;          // 0..3
    const int lane = threadIdx.x & 63;
    const int row  = blockIdx.x * 4 + wave;
    const float4* p = reinterpret_cast<const float4*>(E + (size_t)row * DIM) + lane * 2;
    float4 a = p[0], b = p[1];
    float s = a.x * a.x + a.y * a.y + a.z * a.z + a.w * a.w
            + b.x * b.x + b.y * b.y + b.z * b.z + b.w * b.w;
    #pragma unroll
    for (int off = 32; off > 0; off >>= 1) s += __shfl_down(s, off, 64);
    if (lane == 0) e_sq[row] = s;
}

// ---------------------------------------------------------------------------
// Kernel 2: tiled fp32 GEMM (X @ E^T) with fused running argmax of
//           s = 2*dot - e_sq over this block's K-chunk.
//   grid = (KSPLIT, N_ROWS/BM), block = 256 threads.
// ---------------------------------------------------------------------------
__global__ __launch_bounds__(256, 4)
void argmax_gemm_kernel(const float* __restrict__ X, const float* __restrict__ E,
                        const float* __restrict__ e_sq,
                        float* __restrict__ part_s, int* __restrict__ part_i) {
    __shared__ float Xs[BD][LDE];   // Xs[d][m]
    __shared__ float Es[BD][LDE];   // Es[d][n]
    __shared__ float red_s[BM][16];
    __shared__ int   red_i[BM][16];

    const int row0  = blockIdx.y * BM;
    const int code0 = blockIdx.x * KCHUNK;
    const int tid = threadIdx.x;
    const int tx = tid & 15;        // code sub-tile 0..15
    const int ty = tid >> 4;        // row  sub-tile 0..15

    float best_s[4];
    int   best_i[4];
    #pragma unroll
    for (int i = 0; i < 4; ++i) { best_s[i] = -INFINITY; best_i[i] = 0; }

    for (int nt = 0; nt < KCHUNK / BN; ++nt) {        // 8 code tiles
        const int n0 = code0 + nt * BN;
        float acc[4][4] = {};

        for (int d0 = 0; d0 < DIM; d0 += BD) {        // 16 depth tiles
            // Stage X tile and E tile (each 64 rows x 32 depth), transposed.
            #pragma unroll
            for (int p = 0; p < 2; ++p) {
                const int idx = p * 256 + tid;        // 0..511
                const int r   = idx >> 3;             // 0..63
                const int c   = (idx & 7) << 2;       // 0,4,...,28
                float4 v = *reinterpret_cast<const float4*>(
                    X + (size_t)(row0 + r) * DIM + d0 + c);
                Xs[c + 0][r] = v.x; Xs[c + 1][r] = v.y;
                Xs[c + 2][r] = v.z; Xs[c + 3][r] = v.w;
                float4 w = *reinterpret_cast<const float4*>(
                    E + (size_t)(n0 + r) * DIM + d0 + c);
                Es[c + 0][r] = w.x; Es[c + 1][r] = w.y;
                Es[c + 2][r] = w.z; Es[c + 3][r] = w.w;
            }
            __syncthreads();

            #pragma unroll
            for (int k = 0; k < BD; ++k) {
                float4 av = *reinterpret_cast<const float4*>(&Xs[k][ty * 4]);
                float4 bv = *reinterpret_cast<const float4*>(&Es[k][tx * 4]);
                float a[4] = {av.x, av.y, av.z, av.w};
                float b[4] = {bv.x, bv.y, bv.z, bv.w};
                #pragma unroll
                for (int i = 0; i < 4; ++i)
                    #pragma unroll
                    for (int j = 0; j < 4; ++j)
                        acc[i][j] = fmaf(a[i], b[j], acc[i][j]);
            }
            __syncthreads();
        }

        // Fold this code tile into the running argmax.
        #pragma unroll
        for (int j = 0; j < 4; ++j) {
            const int code = n0 + tx * 4 + j;
            const float es = e_sq[code];
            #pragma unroll
            for (int i = 0; i < 4; ++i) {
                const float s = 2.0f * acc[i][j] - es;
                if (s > best_s[i]) { best_s[i] = s; best_i[i] = code; }
            }
        }
    }

    // Cross-thread reduce: 16 candidates per row.
    #pragma unroll
    for (int i = 0; i < 4; ++i) {
        red_s[ty * 4 + i][tx] = best_s[i];
        red_i[ty * 4 + i][tx] = best_i[i];
    }
    __syncthreads();
    if (tid < BM) {
        float bs = red_s[tid][0];
        int   bi = red_i[tid][0];
        #pragma unroll
        for (int j = 1; j < 16; ++j) {
            const float s = red_s[tid][j];
            const int   ii = red_i[tid][j];
            if (s > bs || (s == bs && ii < bi)) { bs = s; bi = ii; }
        }
        const int row = row0 + tid;
        part_s[(size_t)row * KSPLIT + blockIdx.x] = bs;
        part_i[(size_t)row * KSPLIT + blockIdx.x] = bi;
    }
}

// ---------------------------------------------------------------------------
// Kernel 3: reduce KSPLIT partials per row, write index (as float) + gather.
//   grid = N_ROWS, block = 128 threads (128 x float4 = 512 floats).
// ---------------------------------------------------------------------------
__global__ void finalize_kernel(const float* __restrict__ part_s,
                                const int* __restrict__ part_i,
                                const float* __restrict__ E,
                                float* __restrict__ out_q,
                                float* __restrict__ out_i) {
    const int row = blockIdx.x;
    __shared__ int s_best;
    if (threadIdx.x == 0) {
        float bs = part_s[(size_t)row * KSPLIT];
        int   bi = part_i[(size_t)row * KSPLIT];
        #pragma unroll
        for (int j = 1; j < KSPLIT; ++j) {
            const float s = part_s[(size_t)row * KSPLIT + j];
            const int  ii = part_i[(size_t)row * KSPLIT + j];
            if (s > bs || (s == bs && ii < bi)) { bs = s; bi = ii; }
        }
        s_best = bi;
        out_i[row] = (float)bi;
    }
    __syncthreads();
    const int bi = s_best;
    const float4* src = reinterpret_cast<const float4*>(E + (size_t)bi * DIM);
    float4* dst = reinterpret_cast<float4*>(out_q + (size_t)row * DIM);
    dst[threadIdx.x] = src[threadIdx.x];
}

// ---------------------------------------------------------------------------
extern "C" void kernel_launch(void* const* d_in, const int* in_sizes, int n_in,
                              void* d_out, int out_size, void* d_ws, size_t ws_size,
                              hipStream_t stream) {
    const float* X = (const float*)d_in[0];        // [8192, 512]
    const float* E = (const float*)d_in[1];        // [8192, 512]

    float* out_q = (float*)d_out;                               // [8192, 512]
    float* out_i = (float*)d_out + (size_t)N_ROWS * DIM;        // [8192] (as float)

    float* e_sq   = (float*)d_ws;                               // 8192 f
    float* part_s = e_sq + K_CODES;                             // 8192*16 f
    int*   part_i = (int*)(part_s + (size_t)N_ROWS * KSPLIT);   // 8192*16 i

    hipLaunchKernelGGL(esq_kernel, dim3(K_CODES / 4), dim3(256), 0, stream, E, e_sq);

    dim3 grid(KSPLIT, N_ROWS / BM);
    hipLaunchKernelGGL(argmax_gemm_kernel, grid, dim3(256), 0, stream,
                       X, E, e_sq, part_s, part_i);

    hipLaunchKernelGGL(finalize_kernel, dim3(N_ROWS), dim3(128), 0, stream,
                       part_s, part_i, E, out_q, out_i);
}